// Round 16
// baseline (56.551 us; speedup 1.0000x reference)
//
#include <hip/hip_runtime.h>
#include <hip/hip_fp16.h>
#include <math.h>

namespace {

constexpr int SEQ = 2048;
constexpr int BAT = 8;

struct alignas(8) h4 { __half2 lo, hi; };
typedef float f4 __attribute__((ext_vector_type(4)));

// Analytic 8-qubit circuit: z0 = c1..c7 ; zi = c0..ci (ci = cos(theta_i))
__device__ __forceinline__ void qproj8(const float th[8], float z[8]) {
    float c[8];
#pragma unroll
    for (int i = 0; i < 8; ++i) c[i] = __cosf(th[i]);
    z[1] = c[0] * c[1];
#pragma unroll
    for (int i = 2; i < 8; ++i) z[i] = z[i - 1] * c[i];
    float p = c[1] * c[2];
    p *= c[3] * c[4];
    p *= c[5] * c[6];
    p *= c[7];
    z[0] = p;
}

// Pure store-stream kernel for the masked upper triangle (44% of bytes).
// No LDS, no barriers, no loads: structurally identical to the 7 TB/s fill.
__global__ __launch_bounds__(256) void zerofill_kernel(float* __restrict__ attn)
{
    const int bh = blockIdx.x >> 7;        // 0..15
    const int rg = blockIdx.x & 127;       // 16-row band
    const int tid = threadIdx.x;
    const f4 zz = {0.f, 0.f, 0.f, 0.f};
#pragma unroll
    for (int e = 0; e < 16; ++e) {
        const int qrow = rg * 16 + e;
        const int nc = (qrow >> 8) + 1;    // first zero chunk
        f4* arow4 = reinterpret_cast<f4*>(attn + ((size_t)bh * SEQ + qrow) * SEQ);
        const int n4 = (8 - nc) * 64;      // f4 count to zero
        for (int idx = tid; idx < n4; idx += 256)
            arow4[nc * 64 + idx] = zz;     // 4KB contiguous per iteration
    }
}

__global__ __launch_bounds__(512, 4) void fused_kernel(
    const float* __restrict__ vin, const float* __restrict__ kin,
    const float* __restrict__ qin,
    const float* __restrict__ Wq, const float* __restrict__ Wk,
    const float* __restrict__ Wv, const float* __restrict__ Wd,
    float* __restrict__ out,       // (B,S,8)
    float* __restrict__ attn)      // (B,H,S,S)
{
    __shared__ h4 Ksh[2][SEQ];     // [head][k] fp16, 32 KB
    __shared__ h4 Vsh[2][SEQ];     // 32 KB
    __shared__ float Qsh[32][8];   // this block's 32 projected Q rows (both heads)
    __shared__ float ctxsh[32][8]; // both heads' ctx for this block's 32 rows

    const int b    = blockIdx.x >> 6;   // batch
    const int g    = blockIdx.x & 63;   // row group: rows r = g + 64*j, j=0..31
    const int tid  = threadIdx.x;
    const int wave = tid >> 6;
    const int lane = tid & 63;
    const int h    = wave & 1;          // head owned by this wave (row loop)
    const int hc   = h * 4;
    const int jb   = wave >> 1;         // j = it*4 + jb, it=0..7

    float wq[8], wk[8], wv[8];
#pragma unroll
    for (int i = 0; i < 8; ++i) { wq[i] = Wq[i]; wk[i] = Wk[i]; wv[i] = Wv[i]; }

    // ---- stage projected K,V (both heads, fp16) into LDS ----
    for (int r = tid; r < SEQ; r += 512) {
        const float4* k4 = reinterpret_cast<const float4*>(kin + ((size_t)b * SEQ + r) * 8);
        float4 ka = k4[0], kb = k4[1];
        float th[8], z[8];
        th[0] = ka.x + wk[0]; th[1] = ka.y + wk[1]; th[2] = ka.z + wk[2]; th[3] = ka.w + wk[3];
        th[4] = kb.x + wk[4]; th[5] = kb.y + wk[5]; th[6] = kb.z + wk[6]; th[7] = kb.w + wk[7];
        qproj8(th, z);
        h4 t;
        t.lo = __floats2half2_rn(z[0], z[1]); t.hi = __floats2half2_rn(z[2], z[3]);
        Ksh[0][r] = t;
        t.lo = __floats2half2_rn(z[4], z[5]); t.hi = __floats2half2_rn(z[6], z[7]);
        Ksh[1][r] = t;

        const float4* v4 = reinterpret_cast<const float4*>(vin + ((size_t)b * SEQ + r) * 8);
        float4 va = v4[0], vb = v4[1];
        th[0] = va.x + wv[0]; th[1] = va.y + wv[1]; th[2] = va.z + wv[2]; th[3] = va.w + wv[3];
        th[4] = vb.x + wv[4]; th[5] = vb.y + wv[5]; th[6] = vb.z + wv[6]; th[7] = vb.w + wv[7];
        qproj8(th, z);
        t.lo = __floats2half2_rn(z[0], z[1]); t.hi = __floats2half2_rn(z[2], z[3]);
        Vsh[0][r] = t;
        t.lo = __floats2half2_rn(z[4], z[5]); t.hi = __floats2half2_rn(z[6], z[7]);
        Vsh[1][r] = t;
    }

    // ---- stage the block's 32 Q-row projections (no vmem in row loop) ----
    if (tid < 32) {
        const int r = g + 64 * tid;
        const float4* q4 = reinterpret_cast<const float4*>(qin + ((size_t)b * SEQ + r) * 8);
        float4 qa = q4[0], qb = q4[1];
        float th[8], z[8];
        th[0] = qa.x + wq[0]; th[1] = qa.y + wq[1]; th[2] = qa.z + wq[2]; th[3] = qa.w + wq[3];
        th[4] = qb.x + wq[4]; th[5] = qb.y + wq[5]; th[6] = qb.z + wq[6]; th[7] = qb.w + wq[7];
        qproj8(th, z);
#pragma unroll
        for (int i = 0; i < 8; ++i) Qsh[tid][i] = 0.5f * z[i];
    }
    __syncthreads();

    const size_t bh = (size_t)(b * 2 + h);

    for (int it = 0; it < 8; ++it) {
        const int j    = it * 4 + jb;
        const int qrow = g + 64 * j;
        float* arow = attn + (bh * SEQ + (size_t)qrow) * SEQ;
        const int nc = (qrow >> 8) + 1;          // active 256-wide chunks

        // Q from LDS (broadcast read — no vmem, no store drain)
        const float q0 = Qsh[j][hc + 0], q1 = Qsh[j][hc + 1];
        const float q2 = Qsh[j][hc + 2], q3 = Qsh[j][hc + 3];

        // fused logits+exp+ctx; |logit| <= 2 -> constant shift (softmax-invariant)
        float pr[8][4];
        float s = 0.f, c0 = 0.f, c1 = 0.f, c2 = 0.f, c3 = 0.f;
#pragma unroll
        for (int c = 0; c < 8; ++c) {
            if (c < nc) {                         // wave-uniform
#pragma unroll
                for (int i = 0; i < 4; ++i) {
                    const int k = c * 256 + i * 64 + lane;
                    h4 K = Ksh[h][k];             // 8B/lane stride: conflict-free
                    h4 V = Vsh[h][k];
                    float2 ka = __half22float2(K.lo), kb = __half22float2(K.hi);
                    float l = fmaf(q0, ka.x, fmaf(q1, ka.y,
                              fmaf(q2, kb.x, fmaf(q3, kb.y, -2.0f))));
                    float pe = __expf(l);
                    pe = (k <= qrow) ? pe : 0.0f;
                    pr[c][i] = pe;
                    s += pe;
                    float2 va = __half22float2(V.lo), vb = __half22float2(V.hi);
                    c0 += pe * va.x; c1 += pe * va.y;
                    c2 += pe * vb.x; c3 += pe * vb.y;
                }
            }
        }

        // s-only reduce (short critical path), then release attn stores
#pragma unroll
        for (int off = 32; off >= 1; off >>= 1)
            s += __shfl_xor(s, off, 64);
        const float inv = 1.0f / s;

#pragma unroll
        for (int c = 0; c < 8; ++c) {
            if (c < nc) {
                arow[c * 256 +   0 + lane] = pr[c][0] * inv;   // 256B coalesced
                arow[c * 256 +  64 + lane] = pr[c][1] * inv;
                arow[c * 256 + 128 + lane] = pr[c][2] * inv;
                arow[c * 256 + 192 + lane] = pr[c][3] * inv;
            }
        }

        // ctx reduce overlaps with stores draining
#pragma unroll
        for (int off = 32; off >= 1; off >>= 1) {
            c0 += __shfl_xor(c0, off, 64);
            c1 += __shfl_xor(c1, off, 64);
            c2 += __shfl_xor(c2, off, 64);
            c3 += __shfl_xor(c3, off, 64);
        }
        if (lane == 0) {
            ctxsh[j][hc + 0] = c0 * inv; ctxsh[j][hc + 1] = c1 * inv;
            ctxsh[j][hc + 2] = c2 * inv; ctxsh[j][hc + 3] = c3 * inv;
        }
    }

    // ---- fused output projection (both heads present per row) ----
    __syncthreads();
    if (tid < 32) {
        const int r = g + 64 * tid;
        float th[8], z[8];
#pragma unroll
        for (int i = 0; i < 8; ++i) th[i] = ctxsh[tid][i] + Wd[i];
        qproj8(th, z);
        float4* o = reinterpret_cast<float4*>(out + ((size_t)b * SEQ + r) * 8);
        o[0] = make_float4(z[0], z[1], z[2], z[3]);
        o[1] = make_float4(z[4], z[5], z[6], z[7]);
    }
}

} // namespace

extern "C" void kernel_launch(void* const* d_in, const int* in_sizes, int n_in,
                              void* d_out, int out_size, void* d_ws, size_t ws_size,
                              hipStream_t stream) {
    // setup_inputs() dict order: v, k, q, mask, Wq, Wk, Wv, Wd  (all float32)
    const float* v  = (const float*)d_in[0];
    const float* k  = (const float*)d_in[1];
    const float* q  = (const float*)d_in[2];
    // d_in[3] = mask (unused: causal mask implicit; exp(-1e9) underflows to exact 0)
    const float* Wq = (const float*)d_in[4];
    const float* Wk = (const float*)d_in[5];
    const float* Wv = (const float*)d_in[6];
    const float* Wd = (const float*)d_in[7];

    float* out  = (float*)d_out;                  // (B,S,8)
    float* attn = out + (size_t)BAT * SEQ * 8;    // (B,H,S,S)

    // 1) pure store-stream for the masked upper triangle (7 TB/s regime)
    hipLaunchKernelGGL(zerofill_kernel, dim3(16 * 128), dim3(256), 0, stream, attn);
    // 2) compute kernel writes only the active (lower-triangle) chunks
    hipLaunchKernelGGL(fused_kernel, dim3(BAT * 64), dim3(512), 0, stream,
                       v, k, q, Wq, Wk, Wv, Wd, out, attn);
}

// Round 17
// 50.569 us; speedup vs baseline: 1.1183x; 1.1183x over previous
//
#include <hip/hip_runtime.h>
#include <hip/hip_fp16.h>
#include <math.h>

namespace {

constexpr int SEQ = 2048;
constexpr int BAT = 8;

struct alignas(8) h4 { __half2 lo, hi; };
typedef float f4 __attribute__((ext_vector_type(4)));

// Analytic 8-qubit circuit: z0 = c1..c7 ; zi = c0..ci (ci = cos(theta_i))
__device__ __forceinline__ void qproj8(const float th[8], float z[8]) {
    float c[8];
#pragma unroll
    for (int i = 0; i < 8; ++i) c[i] = __cosf(th[i]);
    z[1] = c[0] * c[1];
#pragma unroll
    for (int i = 2; i < 8; ++i) z[i] = z[i - 1] * c[i];
    float p = c[1] * c[2];
    p *= c[3] * c[4];
    p *= c[5] * c[6];
    p *= c[7];
    z[0] = p;
}

__global__ __launch_bounds__(512, 4) void fused_kernel(
    const float* __restrict__ vin, const float* __restrict__ kin,
    const float* __restrict__ qin,
    const float* __restrict__ Wq, const float* __restrict__ Wk,
    const float* __restrict__ Wv, const float* __restrict__ Wd,
    float* __restrict__ out,       // (B,S,8)
    float* __restrict__ attn)      // (B,H,S,S)
{
    __shared__ h4 Ksh[2][SEQ];     // [head][k] fp16, 32 KB
    __shared__ h4 Vsh[2][SEQ];     // 32 KB
    __shared__ float Qsh[32][8];   // this block's 32 projected Q rows (both heads)
    __shared__ float ctxsh[32][8]; // both heads' ctx for this block's 32 rows

    const int b    = blockIdx.x >> 6;   // batch
    const int g    = blockIdx.x & 63;   // row group: rows r = g + 64*j, j=0..31
    const int tid  = threadIdx.x;
    const int wave = tid >> 6;
    const int lane = tid & 63;
    const int h    = wave & 1;          // head owned by this wave (row loop)
    const int hc   = h * 4;
    const int jb   = wave >> 1;         // j = it*4 + jb, it=0..7

    float wq[8], wk[8], wv[8];
#pragma unroll
    for (int i = 0; i < 8; ++i) { wq[i] = Wq[i]; wk[i] = Wk[i]; wv[i] = Wv[i]; }

    // ---- stage projected K,V (both heads, fp16) into LDS ----
    for (int r = tid; r < SEQ; r += 512) {
        const float4* k4 = reinterpret_cast<const float4*>(kin + ((size_t)b * SEQ + r) * 8);
        float4 ka = k4[0], kb = k4[1];
        float th[8], z[8];
        th[0] = ka.x + wk[0]; th[1] = ka.y + wk[1]; th[2] = ka.z + wk[2]; th[3] = ka.w + wk[3];
        th[4] = kb.x + wk[4]; th[5] = kb.y + wk[5]; th[6] = kb.z + wk[6]; th[7] = kb.w + wk[7];
        qproj8(th, z);
        h4 t;
        t.lo = __floats2half2_rn(z[0], z[1]); t.hi = __floats2half2_rn(z[2], z[3]);
        Ksh[0][r] = t;
        t.lo = __floats2half2_rn(z[4], z[5]); t.hi = __floats2half2_rn(z[6], z[7]);
        Ksh[1][r] = t;

        const float4* v4 = reinterpret_cast<const float4*>(vin + ((size_t)b * SEQ + r) * 8);
        float4 va = v4[0], vb = v4[1];
        th[0] = va.x + wv[0]; th[1] = va.y + wv[1]; th[2] = va.z + wv[2]; th[3] = va.w + wv[3];
        th[4] = vb.x + wv[4]; th[5] = vb.y + wv[5]; th[6] = vb.z + wv[6]; th[7] = vb.w + wv[7];
        qproj8(th, z);
        t.lo = __floats2half2_rn(z[0], z[1]); t.hi = __floats2half2_rn(z[2], z[3]);
        Vsh[0][r] = t;
        t.lo = __floats2half2_rn(z[4], z[5]); t.hi = __floats2half2_rn(z[6], z[7]);
        Vsh[1][r] = t;
    }

    // ---- stage the block's 32 Q-row projections (kills all global loads
    //      in the row loop -> no vmcnt drain of in-flight attn stores) ----
    if (tid < 32) {
        const int r = g + 64 * tid;
        const float4* q4 = reinterpret_cast<const float4*>(qin + ((size_t)b * SEQ + r) * 8);
        float4 qa = q4[0], qb = q4[1];
        float th[8], z[8];
        th[0] = qa.x + wq[0]; th[1] = qa.y + wq[1]; th[2] = qa.z + wq[2]; th[3] = qa.w + wq[3];
        th[4] = qb.x + wq[4]; th[5] = qb.y + wq[5]; th[6] = qb.z + wq[6]; th[7] = qb.w + wq[7];
        qproj8(th, z);
#pragma unroll
        for (int i = 0; i < 8; ++i) Qsh[tid][i] = 0.5f * z[i];
    }
    __syncthreads();

    const size_t bh = (size_t)(b * 2 + h);

    for (int it = 0; it < 8; ++it) {
        const int j    = it * 4 + jb;
        const int qrow = g + 64 * j;
        float* arow = attn + (bh * SEQ + (size_t)qrow) * SEQ;
        const int nc = (qrow >> 8) + 1;          // active 256-wide chunks

        // 1) dependency-free zero stores for masked chunks, issued first
        f4* arow4 = reinterpret_cast<f4*>(arow);
        const f4 zz = {0.f, 0.f, 0.f, 0.f};
        for (int c = nc; c < 8; ++c)
            arow4[c * 64 + lane] = zz;

        // 2) Q from LDS (broadcast read — no vmem, no store drain)
        const float q0 = Qsh[j][hc + 0], q1 = Qsh[j][hc + 1];
        const float q2 = Qsh[j][hc + 2], q3 = Qsh[j][hc + 3];

        // 3) fused logits+exp+ctx; |logit| <= 2 -> constant shift (softmax-invariant)
        float pr[8][4];
        float s = 0.f, c0 = 0.f, c1 = 0.f, c2 = 0.f, c3 = 0.f;
#pragma unroll
        for (int c = 0; c < 8; ++c) {
            if (c < nc) {                         // wave-uniform
#pragma unroll
                for (int i = 0; i < 4; ++i) {
                    const int k = c * 256 + i * 64 + lane;
                    h4 K = Ksh[h][k];             // 8B/lane stride: conflict-free
                    h4 V = Vsh[h][k];
                    float2 ka = __half22float2(K.lo), kb = __half22float2(K.hi);
                    float l = fmaf(q0, ka.x, fmaf(q1, ka.y,
                              fmaf(q2, kb.x, fmaf(q3, kb.y, -2.0f))));
                    float pe = __expf(l);
                    pe = (k <= qrow) ? pe : 0.0f;
                    pr[c][i] = pe;
                    s += pe;
                    float2 va = __half22float2(V.lo), vb = __half22float2(V.hi);
                    c0 += pe * va.x; c1 += pe * va.y;
                    c2 += pe * vb.x; c3 += pe * vb.y;
                }
            }
        }

        // 4) s-only reduce (short critical path), then release attn stores
#pragma unroll
        for (int off = 32; off >= 1; off >>= 1)
            s += __shfl_xor(s, off, 64);
        const float inv = 1.0f / s;

#pragma unroll
        for (int c = 0; c < 8; ++c) {
            if (c < nc) {
                arow[c * 256 +   0 + lane] = pr[c][0] * inv;   // 256B coalesced
                arow[c * 256 +  64 + lane] = pr[c][1] * inv;
                arow[c * 256 + 128 + lane] = pr[c][2] * inv;
                arow[c * 256 + 192 + lane] = pr[c][3] * inv;
            }
        }

        // 5) ctx reduce overlaps with stores draining
#pragma unroll
        for (int off = 32; off >= 1; off >>= 1) {
            c0 += __shfl_xor(c0, off, 64);
            c1 += __shfl_xor(c1, off, 64);
            c2 += __shfl_xor(c2, off, 64);
            c3 += __shfl_xor(c3, off, 64);
        }
        if (lane == 0) {
            ctxsh[j][hc + 0] = c0 * inv; ctxsh[j][hc + 1] = c1 * inv;
            ctxsh[j][hc + 2] = c2 * inv; ctxsh[j][hc + 3] = c3 * inv;
        }
    }

    // ---- fused output projection (both heads present per row) ----
    __syncthreads();
    if (tid < 32) {
        const int r = g + 64 * tid;
        float th[8], z[8];
#pragma unroll
        for (int i = 0; i < 8; ++i) th[i] = ctxsh[tid][i] + Wd[i];
        qproj8(th, z);
        float4* o = reinterpret_cast<float4*>(out + ((size_t)b * SEQ + r) * 8);
        o[0] = make_float4(z[0], z[1], z[2], z[3]);
        o[1] = make_float4(z[4], z[5], z[6], z[7]);
    }
}

} // namespace

extern "C" void kernel_launch(void* const* d_in, const int* in_sizes, int n_in,
                              void* d_out, int out_size, void* d_ws, size_t ws_size,
                              hipStream_t stream) {
    // setup_inputs() dict order: v, k, q, mask, Wq, Wk, Wv, Wd  (all float32)
    const float* v  = (const float*)d_in[0];
    const float* k  = (const float*)d_in[1];
    const float* q  = (const float*)d_in[2];
    // d_in[3] = mask (unused: causal mask implicit; exp(-1e9) underflows to exact 0)
    const float* Wq = (const float*)d_in[4];
    const float* Wk = (const float*)d_in[5];
    const float* Wv = (const float*)d_in[6];
    const float* Wd = (const float*)d_in[7];

    float* out  = (float*)d_out;                  // (B,S,8)
    float* attn = out + (size_t)BAT * SEQ * 8;    // (B,H,S,S)

    hipLaunchKernelGGL(fused_kernel, dim3(BAT * 64), dim3(512), 0, stream,
                       v, k, q, Wq, Wk, Wv, Wd, out, attn);
}